// Round 1
// 1201.247 us; speedup vs baseline: 3.0610x; 3.0610x over previous
//
#include <hip/hip_runtime.h>

typedef __attribute__((ext_vector_type(8))) short short8;
typedef __attribute__((ext_vector_type(4))) float fvec4;

#define NW 64
#define NN 144
#define CC 192
#define NH 6
#define LL 32
#define NLON 15
#define TT (NLON*NW*NN)   // 138240

__device__ __forceinline__ float bf2f(ushort v) {
  union { unsigned int u; float f; } x;
  x.u = ((unsigned int)v) << 16;
  return x.f;
}
__device__ __forceinline__ ushort f2bf(float f) {
  union { float f; unsigned int u; } x; x.f = f;
  unsigned int r = (x.u + 0x7FFFu + ((x.u >> 16) & 1u)) >> 16;
  return (ushort)r;
}

// Robust dtype detector (correct for both worlds; returns f32 for this problem).
__device__ bool arr_is_f32(const void* p) {
  const ushort* u = (const ushort*)p;
  int sane = 0;
#pragma unroll
  for (int k = 0; k < 16; ++k) {
    float v = bf2f(u[k * 514]);
    if (__builtin_fabsf(v) < 64.f) ++sane;
  }
  return sane < 16;
}
__device__ __forceinline__ float loadS(const void* p, size_t i, bool f) {
  return f ? ((const float*)p)[i] : bf2f(((const ushort*)p)[i]);
}

// ---------------------------------------------------------------------------
// MFMA fused QKV + attention. One block per (b,w,h); 9 waves, one 16-token
// strip each. All LDS tiles stored FRAGMENT-LINEAR: a wave's ds_read_b128 is
// always (tilebase + lane*16) -> conflict-free by construction.
//
// LDS map (bytes), total 81376 (=> 2 blocks/CU):
//  [0,9216)      qF  [9 strip][64 lane][16B]  q*scale, bf16
//  [9216,18432)  kF  [9 tile ][64 lane][16B]  bf16
//  [18432,28672) vF  [10 blk=(mtk*2+dhalf)][64][16B]  v^T, tokens 144..159 zeroed
//  [28672,35296) bc  bf16[3312]  bias_table[.][w][h]  (epi range is dense!)
//  [35296,81376) union: phase1 Wh [36 tile][64][16B] (36864B)
//                       phase2 P  per-wave [5 mtk][4 ch][16 r][8 j] bf16 (9*5120B)
//
// MFMA 16x16x32 layouts (m89-verified): A/B: row=lane&15, k=(lane>>4)*8+j.
// C/D: col=lane&15, row=(lane>>4)*4+reg.
__global__ __launch_bounds__(576, 5) void attn_mfma(
    const void* __restrict__ x, const void* __restrict__ qkv_w,
    const void* __restrict__ qkv_b, const void* __restrict__ mask,
    const void* __restrict__ bt, float* __restrict__ out) {
  __shared__ __attribute__((aligned(16))) char lds[81376];
  const bool xf = arr_is_f32(x);
  const bool wf = arr_is_f32(qkv_w);   // qkv_b shares policy
  const bool bf = arr_is_f32(bt);
  const int h = blockIdx.x, w = blockIdx.y, bb = blockIdx.z;
  const int tid = threadIdx.x;
  const int lane = tid & 63, wv = tid >> 6;
  const int l15 = lane & 15, lg = lane >> 4;
  const size_t tok0 = ((size_t)bb * NW + w) * NN;

  // ---- preload x A-fragments (6 K-steps of 32) for this wave's strip
  short8 afr[6];
  {
    const size_t xrow = (tok0 + wv * 16 + l15) * CC + lg * 8;
    if (xf) {
      const float* xp = (const float*)x + xrow;
#pragma unroll
      for (int kk = 0; kk < 6; ++kk) {
        fvec4 a = *(const fvec4*)(xp + kk * 32);
        fvec4 b = *(const fvec4*)(xp + kk * 32 + 4);
        short8 r;
        r[0]=f2bf(a[0]); r[1]=f2bf(a[1]); r[2]=f2bf(a[2]); r[3]=f2bf(a[3]);
        r[4]=f2bf(b[0]); r[5]=f2bf(b[1]); r[6]=f2bf(b[2]); r[7]=f2bf(b[3]);
        afr[kk] = r;
      }
    } else {
      const ushort* xp = (const ushort*)x + xrow;
#pragma unroll
      for (int kk = 0; kk < 6; ++kk) afr[kk] = *(const short8*)(xp + kk * 32);
    }
  }

  // ---- stage Wh (head's 96 output cols x 192 K) bf16, fragment-linear
  {
    uint* whd = (uint*)(lds + 35296);
    for (int i = tid; i < 96 * 192 / 2; i += 576) {
      int d0 = i * 2;
      int j = d0 & 7, c15 = (d0 >> 3) & 15, ch = (d0 >> 7) & 3, tile = d0 >> 9;
      int kk = tile / 6, nt = tile - kk * 6;
      int k = kk * 32 + ch * 8 + j;
      int c = nt * 16 + c15;                       // 0..95: q(0-31) k(32-63) v(64-95)
      int grow = (c >> 5) * 192 + h * 32 + (c & 31);
      float f0 = loadS(qkv_w, (size_t)grow * 192 + k, wf);
      float f1 = loadS(qkv_w, (size_t)grow * 192 + k + 1, wf);
      whd[i] = (uint)f2bf(f0) | ((uint)f2bf(f1) << 16);
    }
  }
  // ---- stage compact bias table (epi 0..3311 dense for this (w,h))
  {
    ushort* bcw = (ushort*)(lds + 28672);
    for (int i = tid; i < 3312; i += 576)
      bcw[i] = f2bf(loadS(bt, (size_t)i * 384 + w * 6 + h, bf));
  }
  // ---- zero vT token-tail (tokens 144..159 of the 160-padded K dim of PV)
  if (tid < 256) {
    int half = tid >> 7, off = tid & 127;
    ((uint*)(lds + 18432 + (8 + half) * 1024 + 512))[off] = 0;
  }
  __syncthreads();

  // ---- phase 1: per-head QKV GEMM [144x192]@[192x96], 36 MFMAs/wave
  fvec4 acc[6];
#pragma unroll
  for (int nt = 0; nt < 6; ++nt) acc[nt] = (fvec4){0.f, 0.f, 0.f, 0.f};
  {
    const short8* whf = (const short8*)(lds + 35296);
#pragma unroll
    for (int kk = 0; kk < 6; ++kk) {
#pragma unroll
      for (int nt = 0; nt < 6; ++nt) {
        short8 b = whf[(kk * 6 + nt) * 64 + lane];
        acc[nt] = __builtin_amdgcn_mfma_f32_16x16x32_bf16(afr[kk], b, acc[nt], 0, 0, 0);
      }
    }
  }
  // add qkv bias, pre-scale q by 1/sqrt(32), scatter to fragment-linear q/k/vT
#pragma unroll
  for (int nt = 0; nt < 6; ++nt) {
    int c = nt * 16 + l15;
    int which = c >> 5, dim = c & 31;
    float bv = loadS(qkv_b, which * 192 + h * 32 + dim, wf);
#pragma unroll
    for (int r = 0; r < 4; ++r) {
      float v = acc[nt][r] + bv;
      int t15 = lg * 4 + r;                        // token & 15
      if (nt < 2) {
        v *= 0.17677669529663687f;
        *(ushort*)(lds + wv * 1024 + ((dim >> 3) << 8) + (t15 << 4) + ((dim & 7) << 1)) = f2bf(v);
      } else if (nt < 4) {
        *(ushort*)(lds + 9216 + wv * 1024 + ((dim >> 3) << 8) + (t15 << 4) + ((dim & 7) << 1)) = f2bf(v);
      } else {
        int t = wv * 16 + t15;
        *(ushort*)(lds + 18432 + (((t >> 5) * 2 + (dim >> 4)) << 10) +
                   (((t >> 3) & 3) << 8) + ((dim & 15) << 4) + ((t & 7) << 1)) = f2bf(v);
      }
    }
  }
  __syncthreads();

  // ---- phase 2: attention for this wave's 16-row strip (no more barriers)
  char* PW = lds + 35296 + wv * 5120;
  // zero own P tail (keys 144..159) -- only now is the Wh region dead
  ((uint*)(PW + 4 * 1024 + 512))[lane] = 0;
  ((uint*)(PW + 4 * 1024 + 512))[lane + 64] = 0;

  const short8* qf8 = (const short8*)lds;
  const short8* kf8 = (const short8*)(lds + 9216);
  const short8* vf8 = (const short8*)(lds + 18432);
  const ushort* bc = (const ushort*)(lds + 28672);
  short8 qfr = qf8[wv * 64 + lane];

  int nrow[4], en[4];
#pragma unroll
  for (int r = 0; r < 4; ++r) {
    int n = wv * 16 + lg * 4 + r;                  // D rows: (lane>>4)*4+reg
    nrow[r] = n;
    int z1 = n / 72, r1 = n - z1 * 72;
    int h1 = r1 / 12, w1 = r1 - h1 * 12;
    en[r] = 828 * z1 + 23 * h1 + w1 + 11;
  }
  // S = q̂·K^T with C preloaded as bias+mask (free add via MFMA C-operand)
  fvec4 s[9];
#pragma unroll
  for (int mt = 0; mt < 9; ++mt) {
    int m = mt * 16 + l15;                         // D cols: lane&15
    int z2 = (m >= 72) ? 1 : 0;
    int r2 = m - z2 * 72;
    int h2 = r2 / 12, w2 = r2 - h2 * 12;
    int em = 1656 * z2 + 138 * h2 - w2;
    fvec4 c;
#pragma unroll
    for (int r = 0; r < 4; ++r) {
      float bias = bf2f(bc[en[r] + em]);
      float mk = loadS(mask, (tok0 + nrow[r]) * (size_t)NN + m, xf);
      c[r] = bias + mk;
    }
    short8 kfr = kf8[mt * 64 + lane];
    s[mt] = __builtin_amdgcn_mfma_f32_16x16x32_bf16(qfr, kfr, c, 0, 0, 0);
  }
  // wave-parallel softmax: rows live in (16-lane group, reg); reduce over lanes
  fvec4 sum4;
#pragma unroll
  for (int r = 0; r < 4; ++r) {
    float mx = s[0][r];
#pragma unroll
    for (int mt = 1; mt < 9; ++mt) mx = fmaxf(mx, s[mt][r]);
    mx = fmaxf(mx, __shfl_xor(mx, 1));
    mx = fmaxf(mx, __shfl_xor(mx, 2));
    mx = fmaxf(mx, __shfl_xor(mx, 4));
    mx = fmaxf(mx, __shfl_xor(mx, 8));
    float sm = 0.f;
#pragma unroll
    for (int mt = 0; mt < 9; ++mt) {
      float e = __expf(s[mt][r] - mx);
      s[mt][r] = e;
      sm += e;
    }
    sm += __shfl_xor(sm, 1);
    sm += __shfl_xor(sm, 2);
    sm += __shfl_xor(sm, 4);
    sm += __shfl_xor(sm, 8);
    sum4[r] = sm;
  }
  // write P (bf16, unnormalized) to per-wave fragment-linear scratch
#pragma unroll
  for (int mt = 0; mt < 9; ++mt) {
    char* pb = PW + ((mt >> 1) << 10) + (((mt & 1) * 2 + (l15 >> 3)) << 8) +
               ((l15 & 7) << 1) + (lg << 6);
#pragma unroll
    for (int r = 0; r < 4; ++r)
      *(ushort*)(pb + (r << 4)) = f2bf(s[mt][r]);
  }
  // PV: O[16x32] over K=160 (5 steps of 32; tail is zeros)
  fvec4 o0 = {0.f,0.f,0.f,0.f}, o1 = {0.f,0.f,0.f,0.f};
  const short8* pf8 = (const short8*)PW;
#pragma unroll
  for (int mtk = 0; mtk < 5; ++mtk) {
    short8 pfr = pf8[mtk * 64 + lane];
    short8 va = vf8[(mtk * 2 + 0) * 64 + lane];
    short8 vb = vf8[(mtk * 2 + 1) * 64 + lane];
    o0 = __builtin_amdgcn_mfma_f32_16x16x32_bf16(pfr, va, o0, 0, 0, 0);
    o1 = __builtin_amdgcn_mfma_f32_16x16x32_bf16(pfr, vb, o1, 0, 0, 0);
  }
  // epilogue: normalize and store f32
#pragma unroll
  for (int r = 0; r < 4; ++r) {
    float inv = 1.f / sum4[r];
    float* op = out + (tok0 + nrow[r]) * CC + h * LL + l15;
    op[0]  = o0[r] * inv;
    op[16] = o1[r] * inv;
  }
}

// ---------------------------------------------------------------------------
// Pure-VALU in-place projection on f32 d_out. Block owns 64 rows. (unchanged)
__global__ __launch_bounds__(256) void proj_valu(float* __restrict__ io,
                                                 const void* __restrict__ pw,
                                                 const void* __restrict__ pb) {
  __shared__ ushort A[64 * 192];      // bf16 staged activations
  __shared__ ushort WT[192 * 96];     // half of proj_w, transposed
  const bool pf = arr_is_f32(pw);     // proj_b shares policy
  const int tid = threadIdx.x;
  const size_t m0 = (size_t)blockIdx.x * 64;
  for (int idx = tid; idx < 64 * 192; idx += 256)
    A[idx] = f2bf(io[m0 * CC + idx]);
  const int t = tid >> 2, g = tid & 3;
#pragma unroll
  for (int p = 0; p < 2; ++p) {
    for (int idx = tid; idx < 96 * 192; idx += 256) {
      int r = idx / 192, k = idx - r * 192;
      WT[k * 96 + r] = f2bf(loadS(pw, (size_t)(p * 96 + r) * 192 + k, pf));
    }
    __syncthreads();
    float acc[24];
#pragma unroll
    for (int j = 0; j < 24; ++j) acc[j] = 0.f;
    for (int k = 0; k < 192; ++k) {
      float av = bf2f(A[t * 192 + k]);
      const short8* wp = (const short8*)(WT + k * 96 + g * 24);
      short8 w0 = wp[0], w1 = wp[1], w2 = wp[2];
#pragma unroll
      for (int j = 0; j < 8; ++j) {
        acc[j]      += av * bf2f((ushort)w0[j]);
        acc[8 + j]  += av * bf2f((ushort)w1[j]);
        acc[16 + j] += av * bf2f((ushort)w2[j]);
      }
    }
    fvec4 o[6];
#pragma unroll
    for (int j = 0; j < 24; ++j)
      o[j >> 2][j & 3] = acc[j] + loadS(pb, p * 96 + g * 24 + j, pf);
    __syncthreads();   // all reads of A/WT done before overwrite & restage
#pragma unroll
    for (int q = 0; q < 6; ++q)
      *(fvec4*)(io + (m0 + t) * CC + p * 96 + g * 24 + q * 4) = o[q];
  }
}

// ---------------------------------------------------------------------------
extern "C" void kernel_launch(void* const* d_in, const int* in_sizes, int n_in,
                              void* d_out, int out_size, void* d_ws, size_t ws_size,
                              hipStream_t stream) {
  const void *x = d_in[0], *mask = d_in[1], *qkv_w = d_in[2], *qkv_b = d_in[3],
             *proj_w = d_in[4], *proj_b = d_in[5], *bias_tab = d_in[6];
  for (int i = 0; i < n_in; ++i) {
    switch (in_sizes[i]) {
      case 26542080: x = d_in[i]; break;
      case 19906560: mask = d_in[i]; break;
      case 110592:   qkv_w = d_in[i]; break;
      case 576:      qkv_b = d_in[i]; break;
      case 36864:    proj_w = d_in[i]; break;
      case 192:      proj_b = d_in[i]; break;
      case 1271808:  bias_tab = d_in[i]; break;
      default: break;
    }
  }
  float* out = (float*)d_out;
  attn_mfma<<<dim3(NH, NW, NLON), 576, 0, stream>>>(x, qkv_w, qkv_b, mask, bias_tab, out);
  proj_valu<<<TT / 64, 256, 0, stream>>>(out, proj_w, proj_b);
}

// Round 2
// 573.855 us; speedup vs baseline: 6.4076x; 2.0933x over previous
//
#include <hip/hip_runtime.h>

typedef __attribute__((ext_vector_type(8))) short short8;
typedef __attribute__((ext_vector_type(4))) float fvec4;

#define NW 64
#define NN 144
#define CC 192
#define NH 6
#define LL 32
#define NLON 15
#define TT (NLON*NW*NN)   // 138240

// Pre-transformed weights in device-global memory (written by prep kernel).
__device__ ushort g_WF[6 * 36 * 512];    // per-head frag-linear qkv W  [h][kk6][nt6][lane][8]
__device__ ushort g_PF[6 * 12 * 512];    // frag-linear proj W          [kk6][nt12][lane][8]
__device__ ushort g_BC[64 * 6 * 3312];   // bias_table transposed       [w][h][epi]

__device__ __forceinline__ float bf2f(ushort v) {
  union { unsigned int u; float f; } x;
  x.u = ((unsigned int)v) << 16;
  return x.f;
}
__device__ __forceinline__ ushort f2bf(float f) {
  union { float f; unsigned int u; } x; x.f = f;
  unsigned int r = (x.u + 0x7FFFu + ((x.u >> 16) & 1u)) >> 16;
  return (ushort)r;
}

// Robust dtype detector (needs arrays >= ~16KB; only used on large arrays).
__device__ bool arr_is_f32(const void* p) {
  const ushort* u = (const ushort*)p;
  int sane = 0;
#pragma unroll
  for (int k = 0; k < 16; ++k) {
    float v = bf2f(u[k * 514]);
    if (__builtin_fabsf(v) < 64.f) ++sane;
  }
  return sane < 16;
}
__device__ __forceinline__ float loadS(const void* p, size_t i, bool f) {
  return f ? ((const float*)p)[i] : bf2f(((const ushort*)p)[i]);
}

// ---------------------------------------------------------------------------
// prep: one-time (per launch) weight reorganization. Idempotent.
__global__ __launch_bounds__(256) void prep(const void* __restrict__ qkv_w,
                                            const void* __restrict__ proj_w,
                                            const void* __restrict__ bt) {
  const bool wf = arr_is_f32(qkv_w);
  const bool pf = arr_is_f32(proj_w);
  const bool bf = arr_is_f32(bt);
  const int stride = gridDim.x * blockDim.x;
  const int t0 = blockIdx.x * blockDim.x + threadIdx.x;
  // WF: B-fragment value for (h,kk,nt): row c=nt*16+(lane&15), k=kk*32+(lane>>4)*8+j
  for (int i = t0; i < 6 * 36 * 512; i += stride) {
    int j = i & 7, lane = (i >> 3) & 63, f = i >> 9;   // f = h*36 + kk*6 + nt
    int nt = f % 6, kk = (f / 6) % 6, h = f / 36;
    int c = nt * 16 + (lane & 15);
    int k = kk * 32 + (lane >> 4) * 8 + j;
    int grow = (c >> 5) * 192 + h * 32 + (c & 31);
    g_WF[i] = f2bf(loadS(qkv_w, (size_t)grow * 192 + k, wf));
  }
  // PF: row c = nt*16+(lane&15) of proj_w, k = kk*32+(lane>>4)*8+j
  for (int i = t0; i < 6 * 12 * 512; i += stride) {
    int j = i & 7, lane = (i >> 3) & 63, f = i >> 9;   // f = kk*12 + nt
    int nt = f % 12, kk = f / 12;
    int c = nt * 16 + (lane & 15);
    int k = kk * 32 + (lane >> 4) * 8 + j;
    g_PF[i] = f2bf(loadS(proj_w, (size_t)c * 192 + k, pf));
  }
  // BC: [wh][epi] <- bt[epi][wh]   (wh = w*6+h, 384 cols)
  for (int i = t0; i < 64 * 6 * 3312; i += stride) {
    int e = i % 3312, wh = i / 3312;
    g_BC[i] = f2bf(loadS(bt, (size_t)e * 384 + wh, bf));
  }
}

// ---------------------------------------------------------------------------
// MFMA fused QKV + attention. One block per (b,w,h); 9 waves, one 16-token
// strip each. Fragment-linear LDS; B-fragments read directly from L2-resident
// g_WF. LDS map (47104 B => 3 blocks/CU):
//  [0,9216)      qF [9 strip][64][16B]   q*scale bf16
//  [9216,18432)  kF [9 tile ][64][16B]   bf16
//  [18432,28672) vF [10 blk=(tk*2+dh)][64][16B]  v^T, tokens 144..159 zeroed
//  [28672,47104) P  per-wave 2-tile ping-pong [2][1024B]
__global__ __launch_bounds__(576, 7) void attn_mfma(
    const void* __restrict__ x, const void* __restrict__ qkv_w,
    const void* __restrict__ qkv_b, const void* __restrict__ mask,
    float* __restrict__ out) {
  __shared__ __attribute__((aligned(16))) char lds[47104];
  const bool xf = arr_is_f32(x);
  const bool wf = arr_is_f32(qkv_w);   // qkv_b shares policy
  // XCD-chunked swizzle: 5760 blocks, 8 XCDs, 720/chunk (bijective, 5760%8==0).
  // Chunk order is h-fastest -> all 6 heads of a (b,w) window on one XCD.
  const int i0 = blockIdx.x;
  const int ii = (i0 & 7) * 720 + (i0 >> 3);
  const int h = ii % 6;
  const int g0 = ii / 6;
  const int w = g0 & 63, bb = g0 >> 6;
  const int tid = threadIdx.x;
  const int lane = tid & 63, wv = tid >> 6;
  const int l15 = lane & 15, lg = lane >> 4;
  const size_t tok0 = ((size_t)bb * NW + w) * NN;

  // ---- preload x A-fragments (6 K-steps of 32) for this wave's strip
  short8 afr[6];
  {
    const size_t xrow = (tok0 + wv * 16 + l15) * CC + lg * 8;
    if (xf) {
      const float* xp = (const float*)x + xrow;
#pragma unroll
      for (int kk = 0; kk < 6; ++kk) {
        fvec4 a = *(const fvec4*)(xp + kk * 32);
        fvec4 b = *(const fvec4*)(xp + kk * 32 + 4);
        short8 r;
        r[0]=f2bf(a[0]); r[1]=f2bf(a[1]); r[2]=f2bf(a[2]); r[3]=f2bf(a[3]);
        r[4]=f2bf(b[0]); r[5]=f2bf(b[1]); r[6]=f2bf(b[2]); r[7]=f2bf(b[3]);
        afr[kk] = r;
      }
    } else {
      const ushort* xp = (const ushort*)x + xrow;
#pragma unroll
      for (int kk = 0; kk < 6; ++kk) afr[kk] = *(const short8*)(xp + kk * 32);
    }
  }
  // ---- zero vT token-tail (tokens 144..159 of the 160-padded PV K dim)
  if (tid < 256) {
    int half = tid >> 7, off = tid & 127;
    ((uint*)(lds + 18432 + (8 + half) * 1024 + 512))[off] = 0;
  }

  // ---- phase 1: per-head QKV GEMM [144x192]@[192x96], 36 MFMAs/wave,
  //      B-fragments straight from g_WF (L2-resident, 16B/lane loads)
  fvec4 acc[6];
#pragma unroll
  for (int nt = 0; nt < 6; ++nt) acc[nt] = (fvec4){0.f, 0.f, 0.f, 0.f};
  {
    const short8* WFp = (const short8*)g_WF + (size_t)h * 36 * 64;
#pragma unroll
    for (int kk = 0; kk < 6; ++kk) {
#pragma unroll
      for (int nt = 0; nt < 6; ++nt) {
        short8 b = WFp[(kk * 6 + nt) * 64 + lane];
        acc[nt] = __builtin_amdgcn_mfma_f32_16x16x32_bf16(afr[kk], b, acc[nt], 0, 0, 0);
      }
    }
  }
  // add qkv bias, pre-scale q by 1/sqrt(32), scatter to fragment-linear q/k/vT
#pragma unroll
  for (int nt = 0; nt < 6; ++nt) {
    int c = nt * 16 + l15;
    int which = c >> 5, dim = c & 31;
    float bv = loadS(qkv_b, which * 192 + h * 32 + dim, wf);
#pragma unroll
    for (int r = 0; r < 4; ++r) {
      float v = acc[nt][r] + bv;
      int t15 = lg * 4 + r;                        // token & 15
      if (nt < 2) {
        v *= 0.17677669529663687f;
        *(ushort*)(lds + wv * 1024 + ((dim >> 3) << 8) + (t15 << 4) + ((dim & 7) << 1)) = f2bf(v);
      } else if (nt < 4) {
        *(ushort*)(lds + 9216 + wv * 1024 + ((dim >> 3) << 8) + (t15 << 4) + ((dim & 7) << 1)) = f2bf(v);
      } else {
        int t = wv * 16 + t15;
        *(ushort*)(lds + 18432 + (((t >> 5) * 2 + (dim >> 4)) << 10) +
                   (((t >> 3) & 3) << 8) + ((dim & 15) << 4) + ((t & 7) << 1)) = f2bf(v);
      }
    }
  }
  __syncthreads();   // the only barrier

  // ---- phase 2: attention for this wave's 16-row strip
  const short8* qf8 = (const short8*)lds;
  const short8* kf8 = (const short8*)(lds + 9216);
  const short8* vf8 = (const short8*)(lds + 18432);
  const ushort* bc = g_BC + (size_t)(w * 6 + h) * 3312;   // L1-resident 6.6KB
  short8 qfr = qf8[wv * 64 + lane];

  int nrow[4], en[4];
#pragma unroll
  for (int r = 0; r < 4; ++r) {
    int n = wv * 16 + lg * 4 + r;                  // D rows: (lane>>4)*4+reg
    nrow[r] = n;
    int z1 = n / 72, r1 = n - z1 * 72;
    int h1 = r1 / 12, w1 = r1 - h1 * 12;
    en[r] = 828 * z1 + 23 * h1 + w1 + 11;
  }
  // S = q̂·K^T with C preloaded as bias+mask (free add via MFMA C-operand)
  fvec4 s[9];
#pragma unroll
  for (int mt = 0; mt < 9; ++mt) {
    int m = mt * 16 + l15;                         // D cols: lane&15
    int z2 = (m >= 72) ? 1 : 0;
    int r2 = m - z2 * 72;
    int h2 = r2 / 12, w2 = r2 - h2 * 12;
    int em = 1656 * z2 + 138 * h2 - w2;
    fvec4 c;
#pragma unroll
    for (int r = 0; r < 4; ++r) {
      float bias = bf2f(bc[en[r] + em]);
      float mk = loadS(mask, (tok0 + nrow[r]) * (size_t)NN + m, xf);
      c[r] = bias + mk;
    }
    short8 kfr = kf8[mt * 64 + lane];
    s[mt] = __builtin_amdgcn_mfma_f32_16x16x32_bf16(qfr, kfr, c, 0, 0, 0);
  }
  // wave-parallel softmax: rows in (16-lane group, reg); reduce over 16 lanes
  fvec4 sum4;
#pragma unroll
  for (int r = 0; r < 4; ++r) {
    float mx = s[0][r];
#pragma unroll
    for (int mt = 1; mt < 9; ++mt) mx = fmaxf(mx, s[mt][r]);
    mx = fmaxf(mx, __shfl_xor(mx, 1));
    mx = fmaxf(mx, __shfl_xor(mx, 2));
    mx = fmaxf(mx, __shfl_xor(mx, 4));
    mx = fmaxf(mx, __shfl_xor(mx, 8));
    float sm = 0.f;
#pragma unroll
    for (int mt = 0; mt < 9; ++mt) {
      float e = __expf(s[mt][r] - mx);
      s[mt][r] = e;
      sm += e;
    }
    sm += __shfl_xor(sm, 1);
    sm += __shfl_xor(sm, 2);
    sm += __shfl_xor(sm, 4);
    sm += __shfl_xor(sm, 8);
    sum4[r] = sm;
  }
  // ---- PV with 2-tile ping-pong P scratch (per-wave private, no barriers)
  char* PW = lds + 28672 + wv * 2048;
  fvec4 o0 = {0.f,0.f,0.f,0.f}, o1 = {0.f,0.f,0.f,0.f};
#define WRITE_TILE(tk_)                                                        \
  {                                                                            \
    char* pb0 = PW + (((tk_) & 1) << 10) + ((l15 & 7) << 1) + (lg << 6);       \
    _Pragma("unroll")                                                          \
    for (int half = 0; half < 2; ++half) {                                     \
      int mt = (tk_) * 2 + half;                                               \
      char* pb = pb0 + ((half * 2 + (l15 >> 3)) << 8);                         \
      _Pragma("unroll")                                                        \
      for (int r = 0; r < 4; ++r)                                              \
        *(ushort*)(pb + (r << 4)) = (mt < 9) ? f2bf(s[mt][r]) : (ushort)0;     \
    }                                                                          \
  }
  WRITE_TILE(0)
#pragma unroll
  for (int tk = 0; tk < 5; ++tk) {
    if (tk < 4) WRITE_TILE(tk + 1)
    short8 pfr = *(const short8*)(PW + ((tk & 1) << 10) + lane * 16);
    short8 va = vf8[(tk * 2 + 0) * 64 + lane];
    short8 vb = vf8[(tk * 2 + 1) * 64 + lane];
    o0 = __builtin_amdgcn_mfma_f32_16x16x32_bf16(pfr, va, o0, 0, 0, 0);
    o1 = __builtin_amdgcn_mfma_f32_16x16x32_bf16(pfr, vb, o1, 0, 0, 0);
  }
#undef WRITE_TILE
  // epilogue: normalize and store f32
#pragma unroll
  for (int r = 0; r < 4; ++r) {
    float inv = 1.f / sum4[r];
    float* op = out + (tok0 + nrow[r]) * CC + h * LL + l15;
    op[0]  = o0[r] * inv;
    op[16] = o1[r] * inv;
  }
}

// ---------------------------------------------------------------------------
// MFMA in-place projection. 256 thr = 4 waves; wave owns 16 rows x 192 cols.
// B-fragments direct from L2-resident g_PF; bias via the MFMA C-operand.
// No LDS, no barriers (each wave reads only rows it writes).
__global__ __launch_bounds__(256, 4) void proj_mfma(float* __restrict__ io,
                                                    const void* __restrict__ proj_w,
                                                    const void* __restrict__ pb) {
  const bool pf = arr_is_f32(proj_w);   // proj_b shares policy
  const int tid = threadIdx.x;
  const int lane = tid & 63, wv = tid >> 6;
  const int l15 = lane & 15, lg = lane >> 4;
  const size_t row0 = (size_t)blockIdx.x * 64 + wv * 16;

  // A-fragments: 16 rows of io (f32 -> bf16)
  short8 afr[6];
  {
    const float* xp = io + (row0 + l15) * CC + lg * 8;
#pragma unroll
    for (int kk = 0; kk < 6; ++kk) {
      fvec4 a = *(const fvec4*)(xp + kk * 32);
      fvec4 b = *(const fvec4*)(xp + kk * 32 + 4);
      short8 r;
      r[0]=f2bf(a[0]); r[1]=f2bf(a[1]); r[2]=f2bf(a[2]); r[3]=f2bf(a[3]);
      r[4]=f2bf(b[0]); r[5]=f2bf(b[1]); r[6]=f2bf(b[2]); r[7]=f2bf(b[3]);
      afr[kk] = r;
    }
  }
  fvec4 acc[12];
#pragma unroll
  for (int nt = 0; nt < 12; ++nt) {
    float bv = loadS(pb, nt * 16 + l15, pf);
    acc[nt] = (fvec4){bv, bv, bv, bv};
  }
  const short8* PFp = (const short8*)g_PF;
#pragma unroll
  for (int kk = 0; kk < 6; ++kk) {
#pragma unroll
    for (int nt = 0; nt < 12; ++nt) {
      short8 b = PFp[(kk * 12 + nt) * 64 + lane];
      acc[nt] = __builtin_amdgcn_mfma_f32_16x16x32_bf16(afr[kk], b, acc[nt], 0, 0, 0);
    }
  }
#pragma unroll
  for (int nt = 0; nt < 12; ++nt)
#pragma unroll
    for (int r = 0; r < 4; ++r)
      io[(row0 + lg * 4 + r) * CC + nt * 16 + l15] = acc[nt][r];
}

// ---------------------------------------------------------------------------
extern "C" void kernel_launch(void* const* d_in, const int* in_sizes, int n_in,
                              void* d_out, int out_size, void* d_ws, size_t ws_size,
                              hipStream_t stream) {
  const void *x = d_in[0], *mask = d_in[1], *qkv_w = d_in[2], *qkv_b = d_in[3],
             *proj_w = d_in[4], *proj_b = d_in[5], *bias_tab = d_in[6];
  for (int i = 0; i < n_in; ++i) {
    switch (in_sizes[i]) {
      case 26542080: x = d_in[i]; break;
      case 19906560: mask = d_in[i]; break;
      case 110592:   qkv_w = d_in[i]; break;
      case 576:      qkv_b = d_in[i]; break;
      case 36864:    proj_w = d_in[i]; break;
      case 192:      proj_b = d_in[i]; break;
      case 1271808:  bias_tab = d_in[i]; break;
      default: break;
    }
  }
  float* out = (float*)d_out;
  prep<<<1024, 256, 0, stream>>>(qkv_w, proj_w, bias_tab);
  attn_mfma<<<NH * NW * NLON, 576, 0, stream>>>(x, qkv_w, qkv_b, mask, out);
  proj_mfma<<<TT / 64, 256, 0, stream>>>(out, proj_w, proj_b);
}

// Round 4
// 551.422 us; speedup vs baseline: 6.6682x; 1.0407x over previous
//
#include <hip/hip_runtime.h>
#include <hip/hip_bf16.h>

typedef __attribute__((ext_vector_type(8))) short short8;
typedef __attribute__((ext_vector_type(4))) float fvec4;

#define NW 64
#define NN 144
#define CC 192
#define NH 6
#define LL 32
#define NLON 15
#define TT (NLON*NW*NN)   // 138240

// Pre-transformed weights in device-global memory (written by prep kernel).
__device__ ushort g_WF[6 * 36 * 512];    // per-head frag-linear qkv W  [h][kk6][nt6][lane][8]
__device__ ushort g_PF[6 * 12 * 512];    // frag-linear proj W          [kk6][nt12][lane][8]
__device__ ushort g_BC[64 * 6 * 3312];   // bias_table transposed       [w][h][epi]

__device__ __forceinline__ float bf2f(ushort v) {
  union { unsigned int u; float f; } x;
  x.u = ((unsigned int)v) << 16;
  return x.f;
}
__device__ __forceinline__ ushort f2bf(float f) {
  union { float f; unsigned int u; } x; x.f = f;
  unsigned int r = (x.u + 0x7FFFu + ((x.u >> 16) & 1u)) >> 16;
  return (ushort)r;
}
// packed f32x2 -> bf16x2 (compiler emits v_cvt_pk_bf16_f32; RNE, matches f2bf)
__device__ __forceinline__ uint pack2(float a, float b) {
  __hip_bfloat162 t = __float22bfloat162_rn(make_float2(a, b));
  uint u; __builtin_memcpy(&u, &t, 4); return u;
}

// Robust dtype detector (needs arrays >= ~16KB; only used on large arrays).
__device__ bool arr_is_f32(const void* p) {
  const ushort* u = (const ushort*)p;
  int sane = 0;
#pragma unroll
  for (int k = 0; k < 16; ++k) {
    float v = bf2f(u[k * 514]);
    if (__builtin_fabsf(v) < 64.f) ++sane;
  }
  return sane < 16;
}
__device__ __forceinline__ float loadS(const void* p, size_t i, bool f) {
  return f ? ((const float*)p)[i] : bf2f(((const ushort*)p)[i]);
}

// ---------------------------------------------------------------------------
// prep: one-time (per launch) weight reorganization. Idempotent.
__global__ __launch_bounds__(256) void prep(const void* __restrict__ qkv_w,
                                            const void* __restrict__ proj_w,
                                            const void* __restrict__ bt) {
  const bool wf = arr_is_f32(qkv_w);
  const bool pwf = arr_is_f32(proj_w);
  const bool bf = arr_is_f32(bt);
  const int stride = gridDim.x * blockDim.x;
  const int t0 = blockIdx.x * blockDim.x + threadIdx.x;
  // WF: B-fragment value for (h,kk,nt): row c=nt*16+(lane&15), k=kk*32+(lane>>4)*8+j
  for (int i = t0; i < 6 * 36 * 512; i += stride) {
    int j = i & 7, lane = (i >> 3) & 63, f = i >> 9;   // f = h*36 + kk*6 + nt
    int nt = f % 6, kk = (f / 6) % 6, h = f / 36;
    int c = nt * 16 + (lane & 15);
    int k = kk * 32 + (lane >> 4) * 8 + j;
    int grow = (c >> 5) * 192 + h * 32 + (c & 31);
    g_WF[i] = f2bf(loadS(qkv_w, (size_t)grow * 192 + k, wf));
  }
  // PF: row c = nt*16+(lane&15) of proj_w, k = kk*32+(lane>>4)*8+j
  for (int i = t0; i < 6 * 12 * 512; i += stride) {
    int j = i & 7, lane = (i >> 3) & 63, f = i >> 9;   // f = kk*12 + nt
    int nt = f % 12, kk = f / 12;
    int c = nt * 16 + (lane & 15);
    int k = kk * 32 + (lane >> 4) * 8 + j;
    g_PF[i] = f2bf(loadS(proj_w, (size_t)c * 192 + k, pwf));
  }
  // BC: [wh][epi] <- bt[epi][wh]  (wh fastest -> coalesced reads)
  for (int i = t0; i < 64 * 6 * 3312; i += stride) {
    int wh = i % 384, e = i / 384;
    g_BC[(size_t)wh * 3312 + e] = f2bf(loadS(bt, (size_t)e * 384 + wh, bf));
  }
}

// ---------------------------------------------------------------------------
// MFMA fused QKV + attention, SWAPPED-operand phase 2 (S^T = mfma(K,Q)):
// thread (l15,lg) owns query col n=wv*16+l15, key rows {m: (m&15)>>2 == lg}.
// Softmax max/sum therefore reduce across the 4-lane group {l15, l15+16,
// l15+32, l15+48} via __shfl_xor(16|32) -- round-3 bug was omitting this.
// One block per (b,w,h); 9 waves, one 16-token strip each.
// LDS map (29248 B):
//  [0,9216)      qF [9 strip][64][16B]  q*scale bf16; wave's own slot reused as
//                                       P-redistribution scratch in phase 2
//  [9216,18432)  kF [9 tile ][64][16B]  bf16
//  [18432,28672) vF [10 blk=(tk*2+dh)][64][16B]  v^T, tokens 144..159 zeroed
//  [28672,29248) em_tab int[144]  (bias m-offset table)
// Occupancy: VGPR cap 85 ((576,6)) -> 2 blocks/CU. (576,7)=cap72 spilled
// (round-2: WRITE_SIZE 246MB vs 106MB of output).
__global__ __launch_bounds__(576, 6) void attn_mfma(
    const void* __restrict__ x, const void* __restrict__ qkv_w,
    const void* __restrict__ qkv_b, const void* __restrict__ mask,
    float* __restrict__ out) {
  __shared__ __attribute__((aligned(16))) char lds[29248];
  const bool xf = arr_is_f32(x);
  const bool wf = arr_is_f32(qkv_w);   // qkv_b shares policy
  // XCD-chunked swizzle: 5760 blocks, 8 XCDs, 720/chunk (bijective).
  const int i0 = blockIdx.x;
  const int ii = (i0 & 7) * 720 + (i0 >> 3);
  const int h = ii % 6;
  const int g0 = ii / 6;
  const int w = g0 & 63, bb = g0 >> 6;
  const int tid = threadIdx.x;
  const int lane = tid & 63, wv = tid >> 6;
  const int l15 = lane & 15, lg = lane >> 4;
  const size_t tok0 = ((size_t)bb * NW + w) * NN;

  // ---- preload x A-fragments (6 K-steps of 32) for this wave's strip
  short8 afr[6];
  {
    const size_t xrow = (tok0 + wv * 16 + l15) * CC + lg * 8;
    if (xf) {
      const float* xp = (const float*)x + xrow;
#pragma unroll
      for (int kk = 0; kk < 6; ++kk) {
        fvec4 a = *(const fvec4*)(xp + kk * 32);
        fvec4 b = *(const fvec4*)(xp + kk * 32 + 4);
        union { uint4 u; short8 s; } cv;
        cv.u = make_uint4(pack2(a[0], a[1]), pack2(a[2], a[3]),
                          pack2(b[0], b[1]), pack2(b[2], b[3]));
        afr[kk] = cv.s;
      }
    } else {
      const ushort* xp = (const ushort*)x + xrow;
#pragma unroll
      for (int kk = 0; kk < 6; ++kk) afr[kk] = *(const short8*)(xp + kk * 32);
    }
  }
  // ---- zero vT token-tail (tokens 144..159 of the 160-padded PV K dim)
  if (tid < 256) {
    int half = tid >> 7, off = tid & 127;
    ((uint*)(lds + 18432 + (8 + half) * 1024 + 512))[off] = 0;
  }
  // ---- em table: bias m-offset, em[m] = 1656*z2 + 138*h2 - w2
  if (tid < 144) {
    int z2 = tid / 72, r2 = tid - z2 * 72;
    int h2 = r2 / 12, w2 = r2 - h2 * 12;
    ((int*)(lds + 28672))[tid] = 1656 * z2 + 138 * h2 - w2;
  }

  // ---- phase 1: per-head QKV GEMM [144x192]@[192x96], 36 MFMAs/wave
  fvec4 acc[6];
#pragma unroll
  for (int nt = 0; nt < 6; ++nt) acc[nt] = (fvec4){0.f, 0.f, 0.f, 0.f};
  {
    const short8* WFp = (const short8*)g_WF + (size_t)h * 36 * 64;
#pragma unroll
    for (int kk = 0; kk < 6; ++kk) {
#pragma unroll
      for (int nt = 0; nt < 6; ++nt) {
        short8 b = WFp[(kk * 6 + nt) * 64 + lane];
        acc[nt] = __builtin_amdgcn_mfma_f32_16x16x32_bf16(afr[kk], b, acc[nt], 0, 0, 0);
      }
    }
  }
  // add qkv bias, pre-scale q by 1/sqrt(32), scatter to fragment-linear q/k/vT
#pragma unroll
  for (int nt = 0; nt < 6; ++nt) {
    int c = nt * 16 + l15;
    int which = c >> 5, dim = c & 31;
    float bv = loadS(qkv_b, which * 192 + h * 32 + dim, wf);
#pragma unroll
    for (int r = 0; r < 4; ++r) {
      float v = acc[nt][r] + bv;
      int t15 = lg * 4 + r;                        // token & 15
      if (nt < 2) {
        v *= 0.17677669529663687f;
        *(ushort*)(lds + wv * 1024 + ((dim >> 3) << 8) + (t15 << 4) + ((dim & 7) << 1)) = f2bf(v);
      } else if (nt < 4) {
        *(ushort*)(lds + 9216 + wv * 1024 + ((dim >> 3) << 8) + (t15 << 4) + ((dim & 7) << 1)) = f2bf(v);
      } else {
        int t = wv * 16 + t15;
        *(ushort*)(lds + 18432 + (((t >> 5) * 2 + (dim >> 4)) << 10) +
                   (((t >> 3) & 3) << 8) + ((dim & 15) << 4) + ((t & 7) << 1)) = f2bf(v);
      }
    }
  }
  __syncthreads();   // the only barrier

  // ---- phase 2 (swapped): thread owns query col n = wv*16 + l15.
  const short8* qf8 = (const short8*)lds;
  const short8* kf8 = (const short8*)(lds + 9216);
  const short8* vf8 = (const short8*)(lds + 18432);
  const int* emt = (const int*)(lds + 28672);
  const ushort* bc = g_BC + (size_t)(w * 6 + h) * 3312;
  short8 qfr = qf8[wv * 64 + lane];          // wave's q slot now dead -> P scratch

  const int n_glob = wv * 16 + l15;
  int en;
  {
    int z1 = n_glob / 72, r1 = n_glob - z1 * 72;
    int h1 = r1 / 12, w1 = r1 - h1 * 12;
    en = 828 * z1 + 23 * h1 + w1 + 11;
  }
  const size_t mrow = (tok0 + n_glob) * (size_t)NN;

  // S^T tile for key-tile mt: rows m = mt*16+lg*4+r, col n. C = bias+mask.
  auto qk_tile = [&](int mt) -> fvec4 {
    int4 ev = *(const int4*)(emt + mt * 16 + lg * 4);
    fvec4 cc;
    if (xf) {
      cc = *(const fvec4*)((const float*)mask + mrow + mt * 16 + lg * 4);
    } else {
      const ushort* mp = (const ushort*)mask + mrow + mt * 16 + lg * 4;
      cc[0] = bf2f(mp[0]); cc[1] = bf2f(mp[1]); cc[2] = bf2f(mp[2]); cc[3] = bf2f(mp[3]);
    }
    cc[0] += bf2f(bc[en + ev.x]);
    cc[1] += bf2f(bc[en + ev.y]);
    cc[2] += bf2f(bc[en + ev.z]);
    cc[3] += bf2f(bc[en + ev.w]);
    return __builtin_amdgcn_mfma_f32_16x16x32_bf16(kf8[mt * 64 + lane], qfr, cc, 0, 0, 0);
  };

  char* ps = lds + wv * 1024;                 // wave-private P scratch (1KB)
  const int wo0 = ((((lg >> 1)) * 16 + l15) << 4) + ((lg & 1) << 3);      // parity 0
  const int wo1 = ((((lg >> 1) + 2) * 16 + l15) << 4) + ((lg & 1) << 3);  // parity 1
  float mrun, sum = 0.f;
  fvec4 o0 = {0.f, 0.f, 0.f, 0.f}, o1 = {0.f, 0.f, 0.f, 0.f};

  // ===== chunk A: key tiles mt 0..3 (tk 0..1) =====
  {
    fvec4 sa[4];
#pragma unroll
    for (int i = 0; i < 4; ++i) sa[i] = qk_tile(i);
    float mx = fmaxf(fmaxf(sa[0][0], sa[0][1]), fmaxf(sa[0][2], sa[0][3]));
#pragma unroll
    for (int i = 1; i < 4; ++i)
      mx = fmaxf(mx, fmaxf(fmaxf(sa[i][0], sa[i][1]), fmaxf(sa[i][2], sa[i][3])));
    // group reduction: all 4 lanes holding query n must share one max
    mx = fmaxf(mx, __shfl_xor(mx, 16));
    mx = fmaxf(mx, __shfl_xor(mx, 32));
    mrun = mx;
#pragma unroll
    for (int i = 0; i < 4; ++i)
#pragma unroll
      for (int r = 0; r < 4; ++r) {
        float e = __expf(sa[i][r] - mx);
        sa[i][r] = e;
        sum += e;                              // per-thread partial; reduced at end
      }
    uint pw[8];
#pragma unroll
    for (int i = 0; i < 4; ++i) {
      pw[2 * i]     = pack2(sa[i][0], sa[i][1]);
      pw[2 * i + 1] = pack2(sa[i][2], sa[i][3]);
    }
#pragma unroll
    for (int tk = 0; tk < 2; ++tk) {
      *(uint2*)(ps + wo0) = make_uint2(pw[4 * tk + 0], pw[4 * tk + 1]);   // mt=2tk
      *(uint2*)(ps + wo1) = make_uint2(pw[4 * tk + 2], pw[4 * tk + 3]);   // mt=2tk+1
      short8 pfr = *(const short8*)(ps + lane * 16);
      o0 = __builtin_amdgcn_mfma_f32_16x16x32_bf16(vf8[(tk * 2 + 0) * 64 + lane], pfr, o0, 0, 0, 0);
      o1 = __builtin_amdgcn_mfma_f32_16x16x32_bf16(vf8[(tk * 2 + 1) * 64 + lane], pfr, o1, 0, 0, 0);
    }
  }
  // ===== chunk B: key tiles mt 4..8 (tk 2..4), online rescale =====
  {
    fvec4 sb[5];
#pragma unroll
    for (int i = 0; i < 5; ++i) sb[i] = qk_tile(4 + i);
    float lmx = fmaxf(fmaxf(sb[0][0], sb[0][1]), fmaxf(sb[0][2], sb[0][3]));
#pragma unroll
    for (int i = 1; i < 5; ++i)
      lmx = fmaxf(lmx, fmaxf(fmaxf(sb[i][0], sb[i][1]), fmaxf(sb[i][2], sb[i][3])));
    lmx = fmaxf(lmx, __shfl_xor(lmx, 16));
    lmx = fmaxf(lmx, __shfl_xor(lmx, 32));
    float mx = fmaxf(mrun, lmx);               // group-uniform (mrun uniform too)
    float al = __expf(mrun - mx);
    sum *= al;
#pragma unroll
    for (int r = 0; r < 4; ++r) { o0[r] *= al; o1[r] *= al; }
#pragma unroll
    for (int i = 0; i < 5; ++i)
#pragma unroll
      for (int r = 0; r < 4; ++r) {
        float e = __expf(sb[i][r] - mx);
        sb[i][r] = e;
        sum += e;
      }
    mrun = mx;
    uint pw[12];
#pragma unroll
    for (int i = 0; i < 5; ++i) {
      pw[2 * i]     = pack2(sb[i][0], sb[i][1]);
      pw[2 * i + 1] = pack2(sb[i][2], sb[i][3]);
    }
    pw[10] = 0; pw[11] = 0;                    // key tokens 144..159
#pragma unroll
    for (int ti = 0; ti < 3; ++ti) {
      int tk = ti + 2;
      *(uint2*)(ps + wo0) = make_uint2(pw[4 * ti + 0], pw[4 * ti + 1]);
      *(uint2*)(ps + wo1) = make_uint2(pw[4 * ti + 2], pw[4 * ti + 3]);
      short8 pfr = *(const short8*)(ps + lane * 16);
      o0 = __builtin_amdgcn_mfma_f32_16x16x32_bf16(vf8[(tk * 2 + 0) * 64 + lane], pfr, o0, 0, 0, 0);
      o1 = __builtin_amdgcn_mfma_f32_16x16x32_bf16(vf8[(tk * 2 + 1) * 64 + lane], pfr, o1, 0, 0, 0);
    }
  }
  // epilogue: full softmax denominator for query n = group-reduced sum
  sum += __shfl_xor(sum, 16);
  sum += __shfl_xor(sum, 32);
  float inv = 1.f / sum;
  fvec4 r0, r1;
#pragma unroll
  for (int r = 0; r < 4; ++r) { r0[r] = o0[r] * inv; r1[r] = o1[r] * inv; }
  float* op = out + (tok0 + n_glob) * CC + h * LL + lg * 4;
  *(fvec4*)op = r0;
  *(fvec4*)(op + 16) = r1;
}

// ---------------------------------------------------------------------------
// MFMA in-place projection, swapped operands: D'[c][t] = mfma(W_frag, act_frag).
// 256 thr = 4 waves; wave owns 16 rows; fvec4 stores. No LDS, no barriers.
__global__ __launch_bounds__(256, 5) void proj_mfma(float* __restrict__ io,
                                                    const void* __restrict__ proj_w,
                                                    const void* __restrict__ pb) {
  const bool pwf = arr_is_f32(proj_w);   // proj_b shares policy
  // XCD swizzle matching attn's window->XCD mapping (2160 = 8*270, bijective)
  const int i0 = blockIdx.x;
  const int ii = (i0 & 7) * 270 + (i0 >> 3);
  const int tid = threadIdx.x;
  const int lane = tid & 63, wv = tid >> 6;
  const int l15 = lane & 15, lg = lane >> 4;
  const size_t row0 = (size_t)ii * 64 + wv * 16;

  // B-fragments: activation rows (f32 -> bf16), B[col=t][k]: t=l15, k=lg*8+j
  short8 bfr[6];
  {
    const float* xp = io + (row0 + l15) * CC + lg * 8;
#pragma unroll
    for (int kk = 0; kk < 6; ++kk) {
      fvec4 a = *(const fvec4*)(xp + kk * 32);
      fvec4 b = *(const fvec4*)(xp + kk * 32 + 4);
      union { uint4 u; short8 s; } cv;
      cv.u = make_uint4(pack2(a[0], a[1]), pack2(a[2], a[3]),
                        pack2(b[0], b[1]), pack2(b[2], b[3]));
      bfr[kk] = cv.s;
    }
  }
  fvec4 acc[12];
#pragma unroll
  for (int nt = 0; nt < 12; ++nt) {
    if (pwf) {
      acc[nt] = *(const fvec4*)((const float*)pb + nt * 16 + lg * 4);
    } else {
      const ushort* p = (const ushort*)pb + nt * 16 + lg * 4;
      acc[nt][0] = bf2f(p[0]); acc[nt][1] = bf2f(p[1]);
      acc[nt][2] = bf2f(p[2]); acc[nt][3] = bf2f(p[3]);
    }
  }
  const short8* wf8 = (const short8*)g_PF;
#pragma unroll
  for (int kk = 0; kk < 6; ++kk)
#pragma unroll
    for (int nt = 0; nt < 12; ++nt)
      acc[nt] = __builtin_amdgcn_mfma_f32_16x16x32_bf16(wf8[(kk * 12 + nt) * 64 + lane], bfr[kk], acc[nt], 0, 0, 0);
  // store: io[row0+l15][c = nt*16+lg*4+r]  (vectorized, own rows only)
  float* op = io + (row0 + l15) * CC + lg * 4;
#pragma unroll
  for (int nt = 0; nt < 12; ++nt)
    *(fvec4*)(op + nt * 16) = acc[nt];
}

// ---------------------------------------------------------------------------
extern "C" void kernel_launch(void* const* d_in, const int* in_sizes, int n_in,
                              void* d_out, int out_size, void* d_ws, size_t ws_size,
                              hipStream_t stream) {
  const void *x = d_in[0], *mask = d_in[1], *qkv_w = d_in[2], *qkv_b = d_in[3],
             *proj_w = d_in[4], *proj_b = d_in[5], *bias_tab = d_in[6];
  for (int i = 0; i < n_in; ++i) {
    switch (in_sizes[i]) {
      case 26542080: x = d_in[i]; break;
      case 19906560: mask = d_in[i]; break;
      case 110592:   qkv_w = d_in[i]; break;
      case 576:      qkv_b = d_in[i]; break;
      case 36864:    proj_w = d_in[i]; break;
      case 192:      proj_b = d_in[i]; break;
      case 1271808:  bias_tab = d_in[i]; break;
      default: break;
    }
  }
  float* out = (float*)d_out;
  prep<<<1024, 256, 0, stream>>>(qkv_w, proj_w, bias_tab);
  attn_mfma<<<NH * NW * NLON, 576, 0, stream>>>(x, qkv_w, qkv_b, mask, out);
  proj_mfma<<<TT / 64, 256, 0, stream>>>(out, proj_w, proj_b);
}